// Round 13
// baseline (276.927 us; speedup 1.0000x reference)
//
#include <hip/hip_runtime.h>
#include <hip/hip_bf16.h>
#include <math.h>

#define N_TOK 1024
#define N_ATOM 24576
#define C_S 384
#define NH 4
#define HD 96

typedef __attribute__((ext_vector_type(8))) short short8;   // 8 bf16
typedef __attribute__((ext_vector_type(4))) float f32x4;

// ---- workspace layout (float-slot offsets; audited: each = prev + size) ----
#define OFF_SEGX   0u          // 4096                          -> ends 4096
#define OFF_NSPROJ 4096u       // 512 (384 used)                -> ends 4608
#define OFF_TF1    4608u       // 393216 f32                    -> ends 397824
#define OFF_TF1B   397824u     // tf1 bf16 1024x384 = 196608    -> ends 594432
#define OFF_QKV    594432u     // qkv bf16 1024x1152 = 589824   -> ends 1184256
#define OFF_AOB    1184256u    // ao bf16 1024x384 = 196608     -> ends 1380864
#define OFF_WINB   1380864u    // in_w bf16 1152x384 = 221184   -> ends 1602048
#define OFF_WOUTB  1602048u    // out_w bf16 384x384 = 73728    -> ends 1675776
#define OFF_WF1B   1675776u    // ff1_w bf16 1536x384 = 294912  -> ends 1970688
#define OFF_WF2B   1970688u    // ff2_w bf16 1536x384 = 294912  -> ends 2265600

__device__ inline __hip_bfloat16 f2bf(float x) { return __float2bfloat16(x); }
union BFPack { short8 v; __hip_bfloat16 h[8]; };
__device__ inline short8 pack8(float4 a, float4 b)
{
    BFPack p;
    p.h[0] = f2bf(a.x); p.h[1] = f2bf(a.y); p.h[2] = f2bf(a.z); p.h[3] = f2bf(a.w);
    p.h[4] = f2bf(b.x); p.h[5] = f2bf(b.y); p.h[6] = f2bf(b.z); p.h[7] = f2bf(b.w);
    return p.v;
}

// ---------------------------------------------------------------------------
// k_prep: blocks 0..863 weights->bf16 | 864 fourier/noise/nsproj |
//         865..960 segment-sum (segx zeroed by hipMemsetAsync). R7-proven.
__global__ __launch_bounds__(256) void k_prep(
    const float* __restrict__ in_w, const float* __restrict__ out_w,
    const float* __restrict__ ff1_w, const float* __restrict__ ff2_w,
    __hip_bfloat16* __restrict__ winb, __hip_bfloat16* __restrict__ woutb,
    __hip_bfloat16* __restrict__ wf1b, __hip_bfloat16* __restrict__ wf2b,
    const float* __restrict__ sigma,
    const float* __restrict__ fw, const float* __restrict__ fb,
    const float* __restrict__ nsw, const float* __restrict__ nsb,
    float* __restrict__ nsproj_out,
    const float* __restrict__ x_noisy, const int* __restrict__ a2t,
    float* __restrict__ segx)
{
    __shared__ float emb[256];
    __shared__ float noise[256];
    int tid = threadIdx.x;
    int bid = blockIdx.x;

    if (bid < 864) {            // ---- weights -> bf16 ----
        size_t e8 = (size_t)bid * 256 + tid;
        const float* src; __hip_bfloat16* dst; size_t off;
        if (e8 < 55296)       { src = in_w;  dst = winb;  off = e8; }
        else if (e8 < 73728)  { src = out_w; dst = woutb; off = e8 - 55296; }
        else if (e8 < 147456) { src = ff1_w; dst = wf1b;  off = e8 - 73728; }
        else                  { src = ff2_w; dst = wf2b;  off = e8 - 147456; }
        float4 a = *(const float4*)(src + off * 8);
        float4 b = *(const float4*)(src + off * 8 + 4);
        *(short8*)(dst + off * 8) = pack8(a, b);
        return;
    }
    if (bid == 864) {           // ---- fourier -> noise -> nsproj ----
        float sg = sigma[0];
        if (tid < 128) {
            float fr = expf(-logf(1000.f) * (float)tid / 128.f);
            float x = sg * fr;
            emb[tid]       = cosf(x);
            emb[tid + 128] = sinf(x);
        }
        __syncthreads();
        {
            const float* wr = fw + (size_t)tid * 256;
            float acc = fb[tid];
            for (int i = 0; i < 256; i++) acc += emb[i] * wr[i];
            noise[tid] = acc;
        }
        __syncthreads();
        for (int o = tid; o < 384; o += 256) {
            const float* wr = nsw + (size_t)o * 256;
            float acc = nsb[o];
            for (int i = 0; i < 256; i++) acc += noise[i] * wr[i];
            nsproj_out[o] = acc;
        }
        return;
    }
    {                           // ---- segment sum of coords ----
        int a = (bid - 865) * 256 + tid;
        int t = a2t[a];
        atomicAdd(&segx[t * 4 + 0], x_noisy[a * 3 + 0]);
        atomicAdd(&segx[t * 4 + 1], x_noisy[a * 3 + 1]);
        atomicAdd(&segx[t * 4 + 2], x_noisy[a * 3 + 2]);
        atomicAdd(&segx[t * 4 + 3], 1.f);
    }
}

// ---------------------------------------------------------------------------
__device__ inline float blockReduceSum128(float v, volatile float* sm)
{
    #pragma unroll
    for (int off = 32; off > 0; off >>= 1) v += __shfl_down(v, off);
    if ((threadIdx.x & 63) == 0) sm[threadIdx.x >> 6] = v;
    __syncthreads();
    float r = sm[0] + sm[1];
    __syncthreads();
    return r;
}

// token_feat = LN(s)*g+b + nsproj + (cnt>0 ? mean_x@ce_w.T + ce_b : 0)
__global__ __launch_bounds__(128) void k_tokenfeat(
    const float* __restrict__ s, const float* __restrict__ segx,
    const float* __restrict__ nsproj,
    const float* __restrict__ g, const float* __restrict__ b,
    const float* __restrict__ ce_w, const float* __restrict__ ce_b,
    float* __restrict__ tf, __hip_bfloat16* __restrict__ tfb)
{
    __shared__ float sm[2];
    int t = blockIdx.x, tid = threadIdx.x;
    const float* sr = s + (size_t)t * C_S;
    float x0 = sr[tid], x1 = sr[tid + 128], x2 = sr[tid + 256];
    float total = blockReduceSum128(x0 + x1 + x2, sm);
    float mean = total * (1.f / 384.f);
    float d0 = x0 - mean, d1 = x1 - mean, d2 = x2 - mean;
    float vtot = blockReduceSum128(d0 * d0 + d1 * d1 + d2 * d2, sm);
    float inv = rsqrtf(vtot * (1.f / 384.f) + 1e-5f);
    float cnt = segx[t * 4 + 3];
    float mx0 = 0.f, mx1 = 0.f, mx2 = 0.f;
    int has = cnt > 0.f;
    if (has) {
        float ic = 1.f / cnt;
        mx0 = segx[t * 4 + 0] * ic;
        mx1 = segx[t * 4 + 1] * ic;
        mx2 = segx[t * 4 + 2] * ic;
    }
    float xs[3] = {d0, d1, d2};
    #pragma unroll
    for (int l = 0; l < 3; l++) {
        int c = tid + l * 128;
        float ln = xs[l] * inv * g[c] + b[c];
        float coord = 0.f;
        if (has)
            coord = mx0 * ce_w[c * 3 + 0] + mx1 * ce_w[c * 3 + 1]
                  + mx2 * ce_w[c * 3 + 2] + ce_b[c];
        float v = ln + nsproj[c] + coord;
        tf[(size_t)t * C_S + c] = v;
        tfb[(size_t)t * C_S + c] = f2bf(v);
    }
}

// ---------------------------------------------------------------------------
// plain bf16 MFMA GEMM, bf16 out (qkv): C = A @ W^T + bias  (R5-proven)
__global__ __launch_bounds__(256) void k_gemm_obf(
    const __hip_bfloat16* __restrict__ A, const __hip_bfloat16* __restrict__ W,
    const float* __restrict__ bias, __hip_bfloat16* __restrict__ C,
    int N, int K)
{
    __shared__ __hip_bfloat16 As[64][72];
    __shared__ __hip_bfloat16 Bs[64][72];

    int tid = threadIdx.x;
    int bm = blockIdx.y * 64, bn = blockIdx.x * 64;
    int w = tid >> 6, lane = tid & 63;
    int wr = (w >> 1) * 32, wc = (w & 1) * 32;
    int fr = lane & 15, kg = lane >> 4;
    int sr = tid >> 2, sc = (tid & 3) << 4;

    f32x4 acc[2][2] = {};
    for (int k0 = 0; k0 < K; k0 += 64) {
        const __hip_bfloat16* ag = A + (size_t)(bm + sr) * K + k0 + sc;
        const __hip_bfloat16* wg = W + (size_t)(bn + sr) * K + k0 + sc;
        short8 a0 = *(const short8*)(ag + 0);
        short8 a1 = *(const short8*)(ag + 8);
        short8 b0 = *(const short8*)(wg + 0);
        short8 b1 = *(const short8*)(wg + 8);
        __syncthreads();
        *(short8*)&As[sr][sc + 0] = a0;
        *(short8*)&As[sr][sc + 8] = a1;
        *(short8*)&Bs[sr][sc + 0] = b0;
        *(short8*)&Bs[sr][sc + 8] = b1;
        __syncthreads();

        short8 af[2][2], bf[2][2];
        #pragma unroll
        for (int i = 0; i < 2; ++i)
            #pragma unroll
            for (int kh = 0; kh < 2; ++kh) {
                af[i][kh] = *(const short8*)&As[wr + i * 16 + fr][kh * 32 + kg * 8];
                bf[i][kh] = *(const short8*)&Bs[wc + i * 16 + fr][kh * 32 + kg * 8];
            }
        #pragma unroll
        for (int kh = 0; kh < 2; ++kh)
            #pragma unroll
            for (int i = 0; i < 2; ++i)
                #pragma unroll
                for (int j = 0; j < 2; ++j)
                    acc[i][j] = __builtin_amdgcn_mfma_f32_16x16x32_bf16(
                        af[i][kh], bf[j][kh], acc[i][j], 0, 0, 0);
    }

    #pragma unroll
    for (int i = 0; i < 2; ++i)
        #pragma unroll
        for (int j = 0; j < 2; ++j) {
            int n = bn + wc + j * 16 + fr;
            float bv = bias[n];
            #pragma unroll
            for (int r = 0; r < 4; ++r) {
                int m = bm + wr + i * 16 + kg * 4 + r;
                C[(size_t)m * N + n] = f2bf(acc[i][j][r] + bv);
            }
        }
}

// ---------------------------------------------------------------------------
// MFMA flash attention (R5-proven): block = (32 Q-rows, head).
#define QB 32
#define TB 64

__global__ __launch_bounds__(256) void k_attn(
    const __hip_bfloat16* __restrict__ qkv, __hip_bfloat16* __restrict__ ao)
{
    __shared__ __hip_bfloat16 Ks[TB][104];
    __shared__ __hip_bfloat16 Vt[96][72];
    __shared__ __hip_bfloat16 Ps[QB][72];
    __shared__ float wmax[QB][4];
    __shared__ float wsum[QB][4];

    int tid = threadIdx.x;
    int w = tid >> 6, l = tid & 63;
    int fr = l & 15, kg = l >> 4;
    int row0 = blockIdx.x * QB;
    int h = blockIdx.y;
    const float scale = 0.1020620726f;   // 1/sqrt(96)

    short8 qf[2][3];
    #pragma unroll
    for (int qs = 0; qs < 2; ++qs)
        #pragma unroll
        for (int dg = 0; dg < 3; ++dg)
            qf[qs][dg] = *(const short8*)(qkv
                + (size_t)(row0 + qs * 16 + fr) * 1152 + h * 96 + dg * 32 + kg * 8);

    float m[2][4], lsum[2][4];
    #pragma unroll
    for (int qs = 0; qs < 2; ++qs)
        #pragma unroll
        for (int r = 0; r < 4; ++r) { m[qs][r] = -1e30f; lsum[qs][r] = 0.f; }

    const int myqs = w >> 1;
    const int d0 = (w & 1) * 48;
    f32x4 acc_o[3] = {};

    int st_t = tid >> 2, st_c = (tid & 3) * 24;
    int vt_t = tid & 63, vt_d = (tid >> 6) * 24;

    for (int tile = 0; tile < N_TOK / TB; ++tile) {
        int t0 = tile * TB;
        __syncthreads();
        {
            const __hip_bfloat16* src =
                qkv + (size_t)(t0 + st_t) * 1152 + 384 + h * 96 + st_c;
            short8 k0 = *(const short8*)(src);
            short8 k1 = *(const short8*)(src + 8);
            short8 k2 = *(const short8*)(src + 16);
            *(short8*)&Ks[st_t][st_c + 0]  = k0;
            *(short8*)&Ks[st_t][st_c + 8]  = k1;
            *(short8*)&Ks[st_t][st_c + 16] = k2;
        }
        {
            const __hip_bfloat16* src =
                qkv + (size_t)(t0 + vt_t) * 1152 + 768 + h * 96 + vt_d;
            BFPack p0, p1, p2;
            p0.v = *(const short8*)(src);
            p1.v = *(const short8*)(src + 8);
            p2.v = *(const short8*)(src + 16);
            #pragma unroll
            for (int j = 0; j < 8; ++j) {
                Vt[vt_d + j][vt_t]      = p0.h[j];
                Vt[vt_d + 8 + j][vt_t]  = p1.h[j];
                Vt[vt_d + 16 + j][vt_t] = p2.h[j];
            }
        }
        __syncthreads();

        f32x4 s[2] = {};
        #pragma unroll
        for (int dg = 0; dg < 3; ++dg) {
            short8 kf = *(const short8*)&Ks[w * 16 + fr][dg * 32 + kg * 8];
            s[0] = __builtin_amdgcn_mfma_f32_16x16x32_bf16(qf[0][dg], kf, s[0], 0, 0, 0);
            s[1] = __builtin_amdgcn_mfma_f32_16x16x32_bf16(qf[1][dg], kf, s[1], 0, 0, 0);
        }

        #pragma unroll
        for (int qs = 0; qs < 2; ++qs) {
            float rmax[4];
            #pragma unroll
            for (int r = 0; r < 4; ++r) rmax[r] = s[qs][r] * scale;
            #pragma unroll
            for (int off = 1; off < 16; off <<= 1)
                #pragma unroll
                for (int r = 0; r < 4; ++r)
                    rmax[r] = fmaxf(rmax[r], __shfl_xor(rmax[r], off));
            if (fr == 0)
                #pragma unroll
                for (int r = 0; r < 4; ++r)
                    wmax[qs * 16 + kg * 4 + r][w] = rmax[r];
        }
        __syncthreads();

        float sc_my[4];
        #pragma unroll
        for (int qs = 0; qs < 2; ++qs) {
            float psum[4];
            #pragma unroll
            for (int r = 0; r < 4; ++r) {
                int row = qs * 16 + kg * 4 + r;
                float4 wm = *(const float4*)&wmax[row][0];
                float gm = fmaxf(fmaxf(wm.x, wm.y), fmaxf(wm.z, wm.w));
                float mnew = fmaxf(m[qs][r], gm);
                float scr = __expf(m[qs][r] - mnew);
                float p = __expf(s[qs][r] * scale - mnew);
                m[qs][r] = mnew;
                lsum[qs][r] *= scr;
                if (qs == myqs) sc_my[r] = scr;
                Ps[row][w * 16 + fr] = f2bf(p);
                psum[r] = p;
            }
            #pragma unroll
            for (int off = 1; off < 16; off <<= 1)
                #pragma unroll
                for (int r = 0; r < 4; ++r)
                    psum[r] += __shfl_xor(psum[r], off);
            if (fr == 0)
                #pragma unroll
                for (int r = 0; r < 4; ++r)
                    wsum[qs * 16 + kg * 4 + r][w] = psum[r];
        }
        __syncthreads();

        #pragma unroll
        for (int qs = 0; qs < 2; ++qs)
            #pragma unroll
            for (int r = 0; r < 4; ++r) {
                float4 wsv = *(const float4*)&wsum[qs * 16 + kg * 4 + r][0];
                lsum[qs][r] += wsv.x + wsv.y + wsv.z + wsv.w;
            }

        #pragma unroll
        for (int ds = 0; ds < 3; ++ds)
            #pragma unroll
            for (int r = 0; r < 4; ++r)
                acc_o[ds][r] *= sc_my[r];
        #pragma unroll
        for (int kk = 0; kk < 2; ++kk) {
            short8 pf = *(const short8*)&Ps[myqs * 16 + fr][kk * 32 + kg * 8];
            #pragma unroll
            for (int ds = 0; ds < 3; ++ds) {
                short8 vf = *(const short8*)&Vt[d0 + ds * 16 + fr][kk * 32 + kg * 8];
                acc_o[ds] = __builtin_amdgcn_mfma_f32_16x16x32_bf16(pf, vf, acc_o[ds], 0, 0, 0);
            }
        }
    }

    #pragma unroll
    for (int r = 0; r < 4; ++r) {
        float inv = 1.f / lsum[myqs][r];
        int q = row0 + myqs * 16 + kg * 4 + r;
        #pragma unroll
        for (int ds = 0; ds < 3; ++ds) {
            int d = h * 96 + d0 + ds * 16 + fr;
            ao[(size_t)q * C_S + d] = f2bf(acc_o[ds][r] * inv);
        }
    }
}

// ---------------------------------------------------------------------------
// ffnmega: row-local tail in ONE kernel. Block = 16 token rows, 4 waves.
//   tf2 = ao @ out_w^T + out_b + tf1           (16x384, f32 in LDS)
//   lnh = LN(tf2)*g + b                        (bf16 LDS)
//   h1  = silu(lnh @ ff1_w^T + ff1_b)          (chunked 4x384, bf16 LDS ring)
//   tf3 = tf2 + h1 @ ff2_w^T + ff2_b           (ff2 acc in regs across chunks)
//   tout= tf3 @ co_w^T                          (epilogue fold, R12-validated)
//   out[a] = tout[idx[a]] + co_b                (in-block gather: rows complete)
// B-operands read direct from L2-resident bf16 weights (2.7 MB < 4 MB XCD-L2).
#define RB 16

__global__ __launch_bounds__(256) void k_ffnmega(
    const __hip_bfloat16* __restrict__ ao, const float* __restrict__ tf1,
    const __hip_bfloat16* __restrict__ wout, const float* __restrict__ out_b,
    const float* __restrict__ g, const float* __restrict__ b,
    const __hip_bfloat16* __restrict__ wf1, const float* __restrict__ ff1_b,
    const __hip_bfloat16* __restrict__ wf2, const float* __restrict__ ff2_b,
    const float* __restrict__ co_w, const float* __restrict__ co_b,
    const int* __restrict__ idx, float* __restrict__ out)
{
    __shared__ float tf2s[16][388];          // 24832 B (pitch: 2-way banks, free)
    __shared__ __hip_bfloat16 lnh[16][392];  // 12544 B
    __shared__ __hip_bfloat16 h1c[16][392];  // 12544 B (ff1-chunk ring)
    __shared__ float wpart[4][16][3];
    __shared__ float toutl[16][3];

    int tid = threadIdx.x;
    int w = tid >> 6, lane = tid & 63;
    int fr = lane & 15, kg = lane >> 4;
    int base = blockIdx.x * RB;

    // ---- step 1: outproj. A = ao rows (regs); wave w owns cols w*96..+96 ----
    short8 afa[12];
    #pragma unroll
    for (int ks = 0; ks < 12; ++ks)
        afa[ks] = *(const short8*)(ao + (size_t)(base + fr) * 384 + ks * 32 + kg * 8);

    #pragma unroll
    for (int t = 0; t < 6; ++t) {
        int n0 = w * 96 + t * 16;
        f32x4 acc = {};
        #pragma unroll
        for (int ks = 0; ks < 12; ++ks) {
            short8 bf = *(const short8*)(wout + (size_t)(n0 + fr) * 384 + ks * 32 + kg * 8);
            acc = __builtin_amdgcn_mfma_f32_16x16x32_bf16(afa[ks], bf, acc, 0, 0, 0);
        }
        int n = n0 + fr;
        float bv = out_b[n];
        #pragma unroll
        for (int r = 0; r < 4; ++r) {
            int row = kg * 4 + r;
            tf2s[row][n] = acc[r] + bv + tf1[(size_t)(base + row) * 384 + n];
        }
    }
    __syncthreads();

    // ---- step 2: LN (16-thread group per row) ----
    {
        int row = tid >> 4, l16 = tid & 15;
        float s1 = 0.f, s2 = 0.f;
        #pragma unroll
        for (int j = 0; j < 24; ++j) {
            float v = tf2s[row][l16 + j * 16];
            s1 += v; s2 += v * v;
        }
        #pragma unroll
        for (int o = 1; o < 16; o <<= 1) {
            s1 += __shfl_xor(s1, o);
            s2 += __shfl_xor(s2, o);
        }
        float mean = s1 * (1.f / 384.f);
        float rstd = rsqrtf(s2 * (1.f / 384.f) - mean * mean + 1e-5f);
        #pragma unroll
        for (int j = 0; j < 24; ++j) {
            int c = l16 + j * 16;
            lnh[row][c] = f2bf((tf2s[row][c] - mean) * rstd * g[c] + b[c]);
        }
    }
    __syncthreads();

    // ---- step 3+4: ff1 (chunked) feeding ff2 accumulation ----
    short8 af1[12];
    #pragma unroll
    for (int ks = 0; ks < 12; ++ks)
        af1[ks] = *(const short8*)&lnh[fr][ks * 32 + kg * 8];

    f32x4 acc2[6] = {};
    for (int ch = 0; ch < 4; ++ch) {
        #pragma unroll
        for (int t = 0; t < 6; ++t) {
            int n1 = ch * 384 + w * 96 + t * 16;
            f32x4 acc = {};
            #pragma unroll
            for (int ks = 0; ks < 12; ++ks) {
                short8 bf = *(const short8*)(wf1 + (size_t)(n1 + fr) * 384 + ks * 32 + kg * 8);
                acc = __builtin_amdgcn_mfma_f32_16x16x32_bf16(af1[ks], bf, acc, 0, 0, 0);
            }
            float bv = ff1_b[n1 + fr];
            #pragma unroll
            for (int r = 0; r < 4; ++r) {
                float v = acc[r] + bv;
                v = v / (1.f + __expf(-v));   // silu
                h1c[kg * 4 + r][w * 96 + t * 16 + fr] = f2bf(v);
            }
        }
        __syncthreads();
        #pragma unroll
        for (int ks = 0; ks < 12; ++ks) {
            short8 af2 = *(const short8*)&h1c[fr][ks * 32 + kg * 8];
            #pragma unroll
            for (int t = 0; t < 6; ++t) {
                int n2 = w * 96 + t * 16;
                short8 bf = *(const short8*)(wf2
                    + (size_t)(n2 + fr) * 1536 + ch * 384 + ks * 32 + kg * 8);
                acc2[t] = __builtin_amdgcn_mfma_f32_16x16x32_bf16(af2, bf, acc2[t], 0, 0, 0);
            }
        }
        __syncthreads();   // ring reuse of h1c
    }

    // ---- step 5: ff2 epilogue + residual + co_w fold ----
    float part[4][3] = {};
    #pragma unroll
    for (int t = 0; t < 6; ++t) {
        int n = w * 96 + t * 16 + fr;
        float bv = ff2_b[n];
        float c0 = co_w[n], c1 = co_w[384 + n], c2 = co_w[768 + n];
        #pragma unroll
        for (int r = 0; r < 4; ++r) {
            int row = kg * 4 + r;
            float v = acc2[t][r] + bv + tf2s[row][n];
            part[r][0] += v * c0;
            part[r][1] += v * c1;
            part[r][2] += v * c2;
        }
    }
    #pragma unroll
    for (int o = 1; o < 16; o <<= 1)
        #pragma unroll
        for (int r = 0; r < 4; ++r)
            #pragma unroll
            for (int j = 0; j < 3; ++j)
                part[r][j] += __shfl_xor(part[r][j], o);
    if (fr == 0)
        #pragma unroll
        for (int r = 0; r < 4; ++r)
            #pragma unroll
            for (int j = 0; j < 3; ++j)
                wpart[w][kg * 4 + r][j] = part[r][j];
    __syncthreads();
    if (tid < 48) {
        int row = tid / 3, j = tid % 3;
        toutl[row][j] = wpart[0][row][j] + wpart[1][row][j]
                      + wpart[2][row][j] + wpart[3][row][j] + co_b[j];
    }
    __syncthreads();

    // ---- step 6: in-block gather (this block's 16 tout rows are complete) ----
    for (int a = tid; a < N_ATOM; a += 256) {
        int t = idx[a];
        if ((t >> 4) == (int)blockIdx.x) {
            int r = t & 15;
            out[a * 3 + 0] = toutl[r][0];
            out[a * 3 + 1] = toutl[r][1];
            out[a * 3 + 2] = toutl[r][2];
        }
    }
}

// ---------------------------------------------------------------------------
extern "C" void kernel_launch(void* const* d_in, const int* in_sizes, int n_in,
                              void* d_out, int out_size, void* d_ws, size_t ws_size,
                              hipStream_t stream)
{
    const float* x_noisy   = (const float*)d_in[0];
    const float* s         = (const float*)d_in[1];
    // d_in[2] = z : dead code in the reference (z_cond unused) -> never read
    const float* sigma     = (const float*)d_in[3];
    const int*   a2t       = (const int*)d_in[4];
    const float* fourier_w = (const float*)d_in[5];
    const float* fourier_b = (const float*)d_in[6];
    const float* ns_w      = (const float*)d_in[7];
    const float* ns_b      = (const float*)d_in[8];
    const float* lns_g     = (const float*)d_in[11];
    const float* lns_b     = (const float*)d_in[12];
    const float* ce_w      = (const float*)d_in[15];
    const float* ce_b      = (const float*)d_in[16];
    const float* in_w      = (const float*)d_in[17];
    const float* in_b      = (const float*)d_in[18];
    const float* out_w     = (const float*)d_in[19];
    const float* out_b     = (const float*)d_in[20];
    const float* ffln_g    = (const float*)d_in[21];
    const float* ffln_b    = (const float*)d_in[22];
    const float* ff1_w     = (const float*)d_in[23];
    const float* ff1_b     = (const float*)d_in[24];
    const float* ff2_w     = (const float*)d_in[25];
    const float* ff2_b     = (const float*)d_in[26];
    const float* co_w      = (const float*)d_in[27];
    const float* co_b      = (const float*)d_in[28];

    float* ws  = (float*)d_ws;
    float* out = (float*)d_out;
    __hip_bfloat16* tf1b  = (__hip_bfloat16*)(ws + OFF_TF1B);
    __hip_bfloat16* qkvb  = (__hip_bfloat16*)(ws + OFF_QKV);
    __hip_bfloat16* aob   = (__hip_bfloat16*)(ws + OFF_AOB);
    __hip_bfloat16* winb  = (__hip_bfloat16*)(ws + OFF_WINB);
    __hip_bfloat16* woutb = (__hip_bfloat16*)(ws + OFF_WOUTB);
    __hip_bfloat16* wf1b  = (__hip_bfloat16*)(ws + OFF_WF1B);
    __hip_bfloat16* wf2b  = (__hip_bfloat16*)(ws + OFF_WF2B);

    // 0. zero segx (segsum atomics accumulate into it)
    hipMemsetAsync(ws + OFF_SEGX, 0, 4096 * sizeof(float), stream);
    // 1. prep: weights->bf16 | fourier/nsproj | segsum
    hipLaunchKernelGGL(k_prep, dim3(961), dim3(256), 0, stream,
                       in_w, out_w, ff1_w, ff2_w, winb, woutb, wf1b, wf2b,
                       sigma, fourier_w, fourier_b, ns_w, ns_b,
                       ws + OFF_NSPROJ, x_noisy, a2t, ws + OFF_SEGX);
    // 2. tokenfeat -> tf1 f32 + tf1b bf16
    hipLaunchKernelGGL(k_tokenfeat, dim3(N_TOK), dim3(128), 0, stream,
                       s, ws + OFF_SEGX, ws + OFF_NSPROJ, lns_g, lns_b,
                       ce_w, ce_b, ws + OFF_TF1, tf1b);
    // 3. qkv = tf1 @ in_w^T + in_b -> bf16
    hipLaunchKernelGGL(k_gemm_obf, dim3(18, 16), dim3(256), 0, stream,
                       tf1b, winb, in_b, qkvb, 1152, 384);
    // 4. MFMA flash attention
    hipLaunchKernelGGL(k_attn, dim3(N_TOK / QB, NH), dim3(256), 0, stream,
                       qkvb, aob);
    // 5. row-local tail: outproj+LN+ff1+ff2+co-fold+gather, one kernel
    hipLaunchKernelGGL(k_ffnmega, dim3(N_TOK / RB), dim3(256), 0, stream,
                       aob, ws + OFF_TF1, woutb, out_b, ffln_g, ffln_b,
                       wf1b, ff1_b, wf2b, ff2_b, co_w, co_b, a2t, out);
}